// Round 20
// baseline (235.632 us; speedup 1.0000x reference)
//
#include <hip/hip_runtime.h>
#include <cstdint>
#include <cstddef>

typedef unsigned short u16;
typedef __attribute__((ext_vector_type(8))) short short8;
typedef __attribute__((ext_vector_type(4))) float f32x4;
typedef __attribute__((ext_vector_type(4))) float float4v;
typedef __attribute__((ext_vector_type(4))) u16 u16x4;

__device__ __forceinline__ u16 f2bf(float f) {
  union { float f; uint32_t u; } v; v.f = f;
  uint32_t u = v.u;
  return (u16)((u + 0x7FFFu + ((u >> 16) & 1u)) >> 16);
}
__device__ __forceinline__ float bf2f(u16 s) {
  union { uint32_t u; float f; } v; v.u = ((uint32_t)s) << 16; return v.f;
}

__device__ __forceinline__ float fast_exp2(float x) {
#if __has_builtin(__builtin_amdgcn_exp2f)
  return __builtin_amdgcn_exp2f(x);
#else
  return exp2f(x);
#endif
}

// async global->LDS, 16B per lane, dest = wave-uniform base + lane*16
__device__ __forceinline__ void gload16(const u16* g, u16* l) {
  __builtin_amdgcn_global_load_lds((const __attribute__((address_space(1))) void*)g,
                                   (__attribute__((address_space(3))) void*)l,
                                   16, 0, 0);
}

#define SBAR __builtin_amdgcn_sched_barrier(0)

// ---------------- fused convert f32 -> bf16 for all 4 weight tensors ----------------
__global__ __launch_bounds__(256) void k_cvt4(const float* __restrict__ wqkv, const float* __restrict__ wproj,
                                              const float* __restrict__ w1, const float* __restrict__ w2,
                                              u16* __restrict__ o_qkv, u16* __restrict__ o_proj,
                                              u16* __restrict__ o_w1, u16* __restrict__ o_w2) {
  const int total = 3145728;
  int stride = gridDim.x * 256;
  for (int i = blockIdx.x * 256 + threadIdx.x; i < total; i += stride) {
    const float* src; u16* dst; int loc;
    if (i < 786432)       { src = wqkv;  dst = o_qkv;  loc = i; }
    else if (i < 1048576) { src = wproj; dst = o_proj; loc = i - 786432; }
    else if (i < 2097152) { src = w1;    dst = o_w1;   loc = i - 1048576; }
    else                  { src = w2;    dst = o_w2;   loc = i - 2097152; }
    float4v v = *(const float4v*)(src + (size_t)loc * 4);
    u16x4 o;
    #pragma unroll
    for (int j = 0; j < 4; j++) o[j] = f2bf(v[j]);
    *(u16x4*)(dst + (size_t)loc * 4) = o;
  }
}

// ---------------- layernorm f32 -> bf16 (one block per row of 1024) ----------------
__global__ __launch_bounds__(256) void k_ln(const float* __restrict__ x, const float* __restrict__ g,
                                            const float* __restrict__ b, u16* __restrict__ out) {
  int row = blockIdx.x, tid = threadIdx.x;
  int wid = tid >> 6;
  const float* xr = x + (size_t)row * 1024;
  float4v v = *(const float4v*)(xr + tid * 4);
  float s = v[0] + v[1] + v[2] + v[3];
  float sq = v[0]*v[0] + v[1]*v[1] + v[2]*v[2] + v[3]*v[3];
  #pragma unroll
  for (int m = 1; m <= 32; m <<= 1) { s += __shfl_xor(s, m); sq += __shfl_xor(sq, m); }
  __shared__ float ss[4], ssq[4];
  if ((tid & 63) == 0) { ss[wid] = s; ssq[wid] = sq; }
  __syncthreads();
  s = ss[0] + ss[1] + ss[2] + ss[3];
  sq = ssq[0] + ssq[1] + ssq[2] + ssq[3];
  float mu = s * (1.0f/1024.0f);
  float var = sq * (1.0f/1024.0f) - mu*mu;
  float rs = rsqrtf(var + 1e-5f);
  u16x4 o;
  #pragma unroll
  for (int j = 0; j < 4; j++) {
    float y = (v[j] - mu) * rs * g[tid*4+j] + b[tid*4+j];
    o[j] = f2bf(y);
  }
  *(u16x4*)(out + (size_t)row * 1024 + tid * 4) = o;
}

// ---------------- fused: x1 = x + sum4(P); h2 = LN(x1)*g+b  (one row/block) ----------------
__global__ __launch_bounds__(256) void k_redln(const float* __restrict__ x, const u16* __restrict__ P,
                                               const float* __restrict__ g, const float* __restrict__ b,
                                               float* __restrict__ x1, u16* __restrict__ h2) {
  int row = blockIdx.x, tid = threadIdx.x;
  int wid = tid >> 6;
  size_t off = (size_t)row * 1024 + tid * 4;
  float4v v = *(const float4v*)(x + off);
  #pragma unroll
  for (int z = 0; z < 4; z++) {
    u16x4 p = *(const u16x4*)(P + (size_t)z * 4194304 + off);
    #pragma unroll
    for (int j = 0; j < 4; j++) v[j] += bf2f(p[j]);
  }
  *(float4v*)(x1 + off) = v;
  float s = v[0] + v[1] + v[2] + v[3];
  float sq = v[0]*v[0] + v[1]*v[1] + v[2]*v[2] + v[3]*v[3];
  #pragma unroll
  for (int m = 1; m <= 32; m <<= 1) { s += __shfl_xor(s, m); sq += __shfl_xor(sq, m); }
  __shared__ float ss[4], ssq[4];
  if ((tid & 63) == 0) { ss[wid] = s; ssq[wid] = sq; }
  __syncthreads();
  s = ss[0] + ss[1] + ss[2] + ss[3];
  sq = ssq[0] + ssq[1] + ssq[2] + ssq[3];
  float mu = s * (1.0f/1024.0f);
  float var = sq * (1.0f/1024.0f) - mu*mu;
  float rs = rsqrtf(var + 1e-5f);
  u16x4 o;
  #pragma unroll
  for (int j = 0; j < 4; j++) o[j] = f2bf((v[j] - mu) * rs * g[tid*4+j] + b[tid*4+j]);
  *(u16x4*)(h2 + off) = o;
}

// ================= 256x256 GEMM, BK=64, 2-slot pipeline (green, unchanged) =================
// EPI: 2=bf16 gelu(acc+bias), 4=bf16 plain, 6=bf16 partial at z*M*N
template<int EPI>
__global__ __launch_bounds__(512, 2) void k_g256(const u16* __restrict__ A, const u16* __restrict__ B,
                                                 const float* __restrict__ bias, u16* __restrict__ Cb,
                                                 int M, int N, int K, int Ksub) {
  extern __shared__ __align__(16) u16 smem[];   // [2][2][2][8192] = 128KB
  int tid = threadIdx.x;
  int gx = gridDim.x;
  int lin = blockIdx.y * gx + blockIdx.x;
  int nwg = gx * gridDim.y;
  int cpx = nwg >> 3;
  int swz = (lin & 7) * cpx + (lin >> 3);
  int bx = swz % gx, by = swz / gx;
  int m0 = by * 256, n0 = bx * 256;
  int kbase = blockIdx.z * Ksub;
  int wid = tid >> 6, lane = tid & 63;
  int wm = wid >> 2, wn = wid & 3;
  int l15 = lane & 15, l16 = lane >> 4;

  f32x4 acc[8][4] = {};
  int nt = Ksub >> 6;

  auto STAGE = [&](int bsel, int kb) {
    #pragma unroll
    for (int st = 0; st < 2; st++) {
      u16* abase = smem + bsel*32768 + st*16384;
      u16* bbase = abase + 8192;
      int kbs = kb + st*32;
      #pragma unroll
      for (int i = 0; i < 2; i++) {
        int c = i*512 + tid;
        int R = c >> 3, p = c & 7;
        int sp = p ^ (R & 7);
        int r = 2*R + (sp >> 2);
        int g = sp & 3;
        gload16(A + (size_t)(m0 + r)*K + kbs + g*8, abase + c*8);
        gload16(B + (size_t)(n0 + r)*K + kbs + g*8, bbase + c*8);
      }
    }
  };

  STAGE(0, kbase);

  for (int t = 0; t < nt; ++t) {
    int sl = t & 1;
    asm volatile("s_waitcnt vmcnt(0)" ::: "memory");
    SBAR;
    __builtin_amdgcn_s_barrier();
    SBAR;
    if (t + 1 < nt) STAGE(sl ^ 1, kbase + (t + 1) * 64);
    #pragma unroll
    for (int st = 0; st < 2; st++) {
      const u16* ab = smem + sl*32768 + st*16384;
      const u16* bb = ab + 8192;
      short8 af[8], bf[4];
      #pragma unroll
      for (int mf = 0; mf < 8; mf++) {
        int r = wm*128 + mf*16 + l15;
        int R = r >> 1;
        int sp = ((r & 1)*4 + l16) ^ (R & 7);
        af[mf] = *(const short8*)(ab + R*64 + sp*8);
      }
      #pragma unroll
      for (int nf = 0; nf < 4; nf++) {
        int r = wn*64 + nf*16 + l15;
        int R = r >> 1;
        int sp = ((r & 1)*4 + l16) ^ (R & 7);
        bf[nf] = *(const short8*)(bb + R*64 + sp*8);
      }
      asm volatile("s_waitcnt lgkmcnt(0)" ::: "memory");
      SBAR;
      __builtin_amdgcn_s_setprio(1);
      #pragma unroll
      for (int mf = 0; mf < 8; mf++)
        #pragma unroll
        for (int nf = 0; nf < 4; nf++)
          acc[mf][nf] = __builtin_amdgcn_mfma_f32_16x16x32_bf16(af[mf], bf[nf], acc[mf][nf], 0, 0, 0);
      __builtin_amdgcn_s_setprio(0);
    }
  }

  size_t zoff = (EPI == 6) ? (size_t)blockIdx.z * M * N : 0;
  #pragma unroll
  for (int mf = 0; mf < 8; mf++) {
    #pragma unroll
    for (int nf = 0; nf < 4; nf++) {
      int col = n0 + wn*64 + nf*16 + l15;
      #pragma unroll
      for (int r = 0; r < 4; r++) {
        int row = m0 + wm*128 + mf*16 + l16*4 + r;
        float v = acc[mf][nf][r];
        if constexpr (EPI == 2) { v += bias[col]; v = 0.5f*v*(1.0f + erff(v*0.70710678118f)); }
        Cb[zoff + (size_t)row*N + col] = f2bf(v);
      }
    }
  }
}

// ---------------- reduce: out = base (+bias) + sum_{z<NP} P_z  (f32 out) ----------------
template<int NP, int HASB>
__global__ __launch_bounds__(256) void k_red(const float* __restrict__ base, const float* __restrict__ bias,
                                             const u16* __restrict__ P, size_t zstride, float* __restrict__ out) {
  int i = blockIdx.x * 256 + threadIdx.x;
  float4v v = *(const float4v*)(base + (size_t)i * 4);
  if constexpr (HASB) {
    float4v bb = *(const float4v*)(bias + (size_t)(i & 255) * 4);
    #pragma unroll
    for (int j = 0; j < 4; j++) v[j] += bb[j];
  }
  #pragma unroll
  for (int z = 0; z < NP; z++) {
    u16x4 p = *(const u16x4*)(P + (size_t)z * zstride + (size_t)i * 4);
    #pragma unroll
    for (int j = 0; j < 4; j++) v[j] += bf2f(p[j]);
  }
  *(float4v*)(out + (size_t)i * 4) = v;
}

// ---------------- prep: l2norm q,k (fold temp*log2e into q), V -> V^T ----------------
__global__ __launch_bounds__(256) void k_prep(const u16* __restrict__ qkv, const float* __restrict__ temp,
                                              u16* __restrict__ Qn, u16* __restrict__ Kn, u16* __restrict__ Vt) {
  int grp = blockIdx.x, bh = blockIdx.y;
  int b = bh >> 4, h = bh & 15;
  int tid = threadIdx.x;
  int n0 = grp * 64;
  __shared__ __align__(16) u16 vs[64*64];
  float tmp = temp[h] * 1.44269504f;
  int j8 = tid & 7;
  #pragma unroll
  for (int pass = 0; pass < 2; pass++) {
    int tl = pass*32 + (tid >> 3);
    size_t roff = (size_t)((b*2048) + n0 + tl) * 3072 + h*64 + j8*8;
    short8 q8 = *(const short8*)(qkv + roff);
    short8 k8 = *(const short8*)(qkv + roff + 1024);
    short8 v8 = *(const short8*)(qkv + roff + 2048);
    float qv[8], kv[8];
    float sq = 0.f, sk = 0.f;
    #pragma unroll
    for (int jj = 0; jj < 8; jj++) {
      qv[jj] = bf2f((u16)q8[jj]); sq += qv[jj]*qv[jj];
      kv[jj] = bf2f((u16)k8[jj]); sk += kv[jj]*kv[jj];
    }
    sq += __shfl_xor(sq, 1); sq += __shfl_xor(sq, 2); sq += __shfl_xor(sq, 4);
    sk += __shfl_xor(sk, 1); sk += __shfl_xor(sk, 2); sk += __shfl_xor(sk, 4);
    float qs = tmp / fmaxf(sqrtf(sq), 1e-12f);
    float ksc = 1.0f / fmaxf(sqrtf(sk), 1e-12f);
    short8 qo, ko;
    #pragma unroll
    for (int jj = 0; jj < 8; jj++) {
      qo[jj] = (short)f2bf(qv[jj] * qs);
      ko[jj] = (short)f2bf(kv[jj] * ksc);
    }
    size_t obase = ((size_t)bh*2048 + n0 + tl)*64 + j8*8;
    *(short8*)(Qn + obase) = qo;
    *(short8*)(Kn + obase) = ko;
    *(short8*)&vs[tl*64 + j8*8] = v8;
  }
  __syncthreads();
  int d = tid & 63, chunk = tid >> 6;
  u16 vals[16];
  #pragma unroll
  for (int jj = 0; jj < 16; jj++) vals[jj] = vs[(chunk*16 + jj)*64 + d];
  short8 w0, w1v;
  #pragma unroll
  for (int j = 0; j < 8; j++) { w0[j] = (short)vals[j]; w1v[j] = (short)vals[8+j]; }
  size_t vo = ((size_t)bh*64 + d)*2048 + n0 + chunk*16;
  *(short8*)(Vt + vo) = w0;
  *(short8*)(Vt + vo + 8) = w1v;
}

// ---------------- flash attention v5: v3 + k_g256-style barrier (no per-tile vmcnt drain) ----------------
// Loop top: vmcnt(0) [tile cur landed] -> s_barrier [all waves done reading slot cur^1]
// -> STAGE(cur^1, next) stays in flight across this tile's compute. No end-of-tile drain.
__device__ __forceinline__ int akey(int row) { return (row & 3) | (((row >> 3) & 1) << 2); }

__global__ __launch_bounds__(256) void k_attn(const u16* __restrict__ Qn, const u16* __restrict__ Kn,
                                              const u16* __restrict__ Vt, const float* __restrict__ temp,
                                              u16* __restrict__ Out) {
  __shared__ __align__(16) u16 Ks[2][64*64];
  __shared__ __align__(16) u16 Vs[2][64*64];
  int lin = blockIdx.y * gridDim.x + blockIdx.x;
  int c = lin & 7, t5 = lin >> 3;
  int bh = c*4 + (t5 >> 4);
  int qg = t5 & 15;
  int b = bh >> 4, h = bh & 15;
  int tid = threadIdx.x, wid = tid >> 6, lane = tid & 63;
  int l15 = lane & 15, l16 = lane >> 4;
  size_t base = (size_t)bh * 2048 * 64;
  size_t vbase = (size_t)bh * 64 * 2048;
  int q0 = qg*128 + wid*32;
  float m2 = fabsf(temp[h]) * 1.44269504f;
  short8 qf[2][2];
  #pragma unroll
  for (int g = 0; g < 2; g++)
    #pragma unroll
    for (int ks = 0; ks < 2; ks++)
      qf[g][ks] = *(const short8*)(Qn + base + (size_t)(q0 + g*16 + l15)*64 + ks*32 + l16*8);
  f32x4 o[2][4] = {};
  float lrow[2] = {0.f, 0.f};
  int prow = (l15 & 3) + 8*(l15 >> 2);

  auto STAGE = [&](int bsel, int kv0) {
    #pragma unroll
    for (int i = 0; i < 2; i++) {
      int cc = i*256 + tid;
      int row = cc >> 3, p = cc & 7;
      int g = p ^ akey(row);
      gload16(Kn + base + (size_t)(kv0 + row)*64 + g*8, &Ks[bsel][(i*256 + wid*64)*8]);
      gload16(Vt + vbase + (size_t)row*2048 + kv0 + g*8, &Vs[bsel][(i*256 + wid*64)*8]);
    }
  };

  STAGE(0, 0);
  int cur = 0;
  for (int kv0 = 0; kv0 < 2048; kv0 += 64) {
    asm volatile("s_waitcnt vmcnt(0)" ::: "memory");   // tile cur landed (wave-local)
    SBAR;
    __builtin_amdgcn_s_barrier();                      // all waves: tile cur visible, cur^1 reads done
    SBAR;
    if (kv0 + 64 < 2048) STAGE(cur ^ 1, kv0 + 64);     // in flight across this tile's compute
    f32x4 s[2][4];
    #pragma unroll
    for (int g = 0; g < 2; g++)
      #pragma unroll
      for (int ss = 0; ss < 4; ss++)
        s[g][ss] = f32x4{-m2, -m2, -m2, -m2};
    __builtin_amdgcn_s_setprio(1);
    #pragma unroll
    for (int dks = 0; dks < 2; dks++) {
      #pragma unroll
      for (int ss = 0; ss < 4; ss++) {
        int row = (ss & 1)*4 + (ss >> 1)*32 + prow;
        short8 kf = *(const short8*)&Ks[cur][row*64 + ((dks*4 + l16) ^ akey(row))*8];
        s[0][ss] = __builtin_amdgcn_mfma_f32_16x16x32_bf16(kf, qf[0][dks], s[0][ss], 0, 0, 0);
        s[1][ss] = __builtin_amdgcn_mfma_f32_16x16x32_bf16(kf, qf[1][dks], s[1][ss], 0, 0, 0);
      }
    }
    __builtin_amdgcn_s_setprio(0);
    short8 pf[2][2];
    #pragma unroll
    for (int g = 0; g < 2; g++) {
      float tsum = 0.f;
      #pragma unroll
      for (int kvs = 0; kvs < 2; kvs++) {
        float e[8];
        #pragma unroll
        for (int r = 0; r < 4; r++) {
          e[r]   = fast_exp2(s[g][kvs*2][r]);
          e[4+r] = fast_exp2(s[g][kvs*2+1][r]);
        }
        #pragma unroll
        for (int r = 0; r < 8; r++) tsum += e[r];
        union { uint32_t u[4]; short8 v; } pu;
        #pragma unroll
        for (int w = 0; w < 4; w++) {
          uint32_t pk;
          asm("v_cvt_pk_bf16_f32 %0, %1, %2" : "=v"(pk) : "v"(e[2*w]), "v"(e[2*w+1]));
          pu.u[w] = pk;
        }
        pf[g][kvs] = pu.v;
      }
      lrow[g] += tsum;
    }
    __builtin_amdgcn_s_setprio(1);
    #pragma unroll
    for (int kvs = 0; kvs < 2; kvs++) {
      short8 vf[4];
      #pragma unroll
      for (int dt = 0; dt < 4; dt++) {
        int row = dt*16 + l15;
        vf[dt] = *(const short8*)&Vs[cur][row*64 + (((kvs*4 + l16) ^ akey(row))*8)];
      }
      #pragma unroll
      for (int dt = 0; dt < 4; dt++) {
        o[0][dt] = __builtin_amdgcn_mfma_f32_16x16x32_bf16(vf[dt], pf[0][kvs], o[0][dt], 0, 0, 0);
        o[1][dt] = __builtin_amdgcn_mfma_f32_16x16x32_bf16(vf[dt], pf[1][kvs], o[1][dt], 0, 0, 0);
      }
    }
    __builtin_amdgcn_s_setprio(0);
    cur ^= 1;
  }
  #pragma unroll
  for (int g = 0; g < 2; g++) {
    float l = lrow[g];
    l += __shfl_xor(l, 16);
    l += __shfl_xor(l, 32);
    float rl = 1.0f / l;
    int tok = b*2048 + q0 + g*16 + l15;
    #pragma unroll
    for (int dt = 0; dt < 4; dt++) {
      u16x4 ov;
      #pragma unroll
      for (int r = 0; r < 4; r++) ov[r] = f2bf(o[g][dt][r] * rl);
      *(u16x4*)(Out + (size_t)tok*1024 + h*64 + dt*16 + l16*4) = ov;
    }
  }
}

// ---------------- workspace layout (bytes) ----------------
static constexpr size_t OFF_WQKV  = 0;
static constexpr size_t OFF_WPROJ = OFF_WQKV  + 6291456;
static constexpr size_t OFF_W1    = OFF_WPROJ + 2097152;
static constexpr size_t OFF_W2    = OFF_W1    + 8388608;
static constexpr size_t OFF_HBF   = OFF_W2    + 8388608;
static constexpr size_t OFF_QKVBF = OFF_HBF   + 8388608;
static constexpr size_t OFF_QN    = OFF_QKVBF + 25165824;
static constexpr size_t OFF_KN    = OFF_QN    + 8388608;
static constexpr size_t OFF_VT    = OFF_KN    + 8388608;
static constexpr size_t OFF_AOUT  = OFF_VT    + 8388608;
static constexpr size_t OFF_H2BF  = OFF_AOUT  + 8388608;
static constexpr size_t OFF_X1    = OFF_H2BF  + 8388608;
static constexpr size_t OFF_HID   = OFF_X1    + 16777216;

extern "C" void kernel_launch(void* const* d_in, const int* in_sizes, int n_in,
                              void* d_out, int out_size, void* d_ws, size_t ws_size,
                              hipStream_t stream) {
  (void)in_sizes; (void)n_in; (void)out_size; (void)ws_size;
  const float* x     = (const float*)d_in[0];
  const float* ln1g  = (const float*)d_in[1];
  const float* ln1b  = (const float*)d_in[2];
  const float* wqkv  = (const float*)d_in[3];
  const float* wproj = (const float*)d_in[4];
  const float* temp  = (const float*)d_in[5];
  const float* ln2g  = (const float*)d_in[6];
  const float* ln2b  = (const float*)d_in[7];
  const float* w1    = (const float*)d_in[8];
  const float* b1    = (const float*)d_in[9];
  const float* w2    = (const float*)d_in[10];
  const float* b2    = (const float*)d_in[11];

  char* ws = (char*)d_ws;
  u16* wqkv_bf  = (u16*)(ws + OFF_WQKV);
  u16* wproj_bf = (u16*)(ws + OFF_WPROJ);
  u16* w1_bf    = (u16*)(ws + OFF_W1);
  u16* w2_bf    = (u16*)(ws + OFF_W2);
  u16* h_bf     = (u16*)(ws + OFF_HBF);
  u16* h2_bf    = (u16*)(ws + OFF_H2BF);
  u16* qkv_bf   = (u16*)(ws + OFF_QKVBF);
  u16* Qn       = (u16*)(ws + OFF_QN);
  u16* Kn       = (u16*)(ws + OFF_KN);
  u16* Vt       = (u16*)(ws + OFF_VT);
  u16* aout_bf  = (u16*)(ws + OFF_AOUT);
  float* x1     = (float*)(ws + OFF_X1);
  u16* hid_bf   = (u16*)(ws + OFF_HID);
  u16* part_p   = (u16*)(ws + OFF_HID);    // proj partials (hid dead then)
  u16* part_m   = (u16*)(ws + OFF_QN);     // mlp2 partials (QN..AOUT dead then)
  float* outf   = (float*)d_out;

  static bool attr_done = false;
  if (!attr_done) {
    hipFuncSetAttribute((const void*)k_g256<2>, hipFuncAttributeMaxDynamicSharedMemorySize, 131072);
    hipFuncSetAttribute((const void*)k_g256<4>, hipFuncAttributeMaxDynamicSharedMemorySize, 131072);
    hipFuncSetAttribute((const void*)k_g256<6>, hipFuncAttributeMaxDynamicSharedMemorySize, 131072);
    attr_done = true;
  }

  // fused weight conversion (one dispatch, grid-stride)
  k_cvt4<<<2048, 256, 0, stream>>>(wqkv, wproj, w1, w2, wqkv_bf, wproj_bf, w1_bf, w2_bf);

  k_ln<<<4096, 256, 0, stream>>>(x, ln1g, ln1b, h_bf);
  k_g256<4><<<dim3(12, 16), 512, 131072, stream>>>(h_bf, wqkv_bf, nullptr, qkv_bf, 4096, 3072, 1024, 1024);
  k_prep<<<dim3(32, 32), 256, 0, stream>>>(qkv_bf, temp, Qn, Kn, Vt);
  k_attn<<<dim3(16, 32), 256, 0, stream>>>(Qn, Kn, Vt, temp, aout_bf);
  // proj split-K=4 partials (at HID) -> fused reduce + LN2
  k_g256<6><<<dim3(4, 16, 4), 512, 131072, stream>>>(aout_bf, wproj_bf, nullptr, part_p, 4096, 1024, 1024, 256);
  k_redln<<<4096, 256, 0, stream>>>(x, part_p, ln2g, ln2b, x1, h2_bf);
  // mlp1: hid = gelu(h2 @ w1^T + b1)
  k_g256<2><<<dim3(16, 16), 512, 131072, stream>>>(h2_bf, w1_bf, b1, hid_bf, 4096, 4096, 1024, 1024);
  // mlp2 split-K=4 partials -> out = x1 + b2 + sum4(P)
  k_g256<6><<<dim3(4, 16, 4), 512, 131072, stream>>>(hid_bf, w2_bf, nullptr, part_m, 4096, 1024, 4096, 1024);
  k_red<4,1><<<4096, 256, 0, stream>>>(x1, b2, part_m, 4194304, outf);
}

// Round 21
// 235.165 us; speedup vs baseline: 1.0020x; 1.0020x over previous
//
#include <hip/hip_runtime.h>
#include <cstdint>
#include <cstddef>

typedef unsigned short u16;
typedef __attribute__((ext_vector_type(8))) short short8;
typedef __attribute__((ext_vector_type(4))) float f32x4;
typedef __attribute__((ext_vector_type(4))) float float4v;
typedef __attribute__((ext_vector_type(4))) u16 u16x4;

__device__ __forceinline__ u16 f2bf(float f) {
  union { float f; uint32_t u; } v; v.f = f;
  uint32_t u = v.u;
  return (u16)((u + 0x7FFFu + ((u >> 16) & 1u)) >> 16);
}
__device__ __forceinline__ float bf2f(u16 s) {
  union { uint32_t u; float f; } v; v.u = ((uint32_t)s) << 16; return v.f;
}

__device__ __forceinline__ float fast_exp2(float x) {
#if __has_builtin(__builtin_amdgcn_exp2f)
  return __builtin_amdgcn_exp2f(x);
#else
  return exp2f(x);
#endif
}

// async global->LDS, 16B per lane, dest = wave-uniform base + lane*16
__device__ __forceinline__ void gload16(const u16* g, u16* l) {
  __builtin_amdgcn_global_load_lds((const __attribute__((address_space(1))) void*)g,
                                   (__attribute__((address_space(3))) void*)l,
                                   16, 0, 0);
}

#define SBAR __builtin_amdgcn_sched_barrier(0)
#define BARR_ do { SBAR; __builtin_amdgcn_s_barrier(); SBAR; } while(0)
#define LG0_  do { asm volatile("s_waitcnt lgkmcnt(0)" ::: "memory"); SBAR; } while(0)
#define VMW4_ do { asm volatile("s_waitcnt vmcnt(4)" ::: "memory"); SBAR; } while(0)
#define VMW0_ do { asm volatile("s_waitcnt vmcnt(0)" ::: "memory"); SBAR; } while(0)

// ---------------- fused convert f32 -> bf16 for all 4 weight tensors ----------------
__global__ __launch_bounds__(256) void k_cvt4(const float* __restrict__ wqkv, const float* __restrict__ wproj,
                                              const float* __restrict__ w1, const float* __restrict__ w2,
                                              u16* __restrict__ o_qkv, u16* __restrict__ o_proj,
                                              u16* __restrict__ o_w1, u16* __restrict__ o_w2) {
  const int total = 3145728;
  int stride = gridDim.x * 256;
  for (int i = blockIdx.x * 256 + threadIdx.x; i < total; i += stride) {
    const float* src; u16* dst; int loc;
    if (i < 786432)       { src = wqkv;  dst = o_qkv;  loc = i; }
    else if (i < 1048576) { src = wproj; dst = o_proj; loc = i - 786432; }
    else if (i < 2097152) { src = w1;    dst = o_w1;   loc = i - 1048576; }
    else                  { src = w2;    dst = o_w2;   loc = i - 2097152; }
    float4v v = *(const float4v*)(src + (size_t)loc * 4);
    u16x4 o;
    #pragma unroll
    for (int j = 0; j < 4; j++) o[j] = f2bf(v[j]);
    *(u16x4*)(dst + (size_t)loc * 4) = o;
  }
}

// ---------------- layernorm f32 -> bf16 (one block per row of 1024) ----------------
__global__ __launch_bounds__(256) void k_ln(const float* __restrict__ x, const float* __restrict__ g,
                                            const float* __restrict__ b, u16* __restrict__ out) {
  int row = blockIdx.x, tid = threadIdx.x;
  int wid = tid >> 6;
  const float* xr = x + (size_t)row * 1024;
  float4v v = *(const float4v*)(xr + tid * 4);
  float s = v[0] + v[1] + v[2] + v[3];
  float sq = v[0]*v[0] + v[1]*v[1] + v[2]*v[2] + v[3]*v[3];
  #pragma unroll
  for (int m = 1; m <= 32; m <<= 1) { s += __shfl_xor(s, m); sq += __shfl_xor(sq, m); }
  __shared__ float ss[4], ssq[4];
  if ((tid & 63) == 0) { ss[wid] = s; ssq[wid] = sq; }
  __syncthreads();
  s = ss[0] + ss[1] + ss[2] + ss[3];
  sq = ssq[0] + ssq[1] + ssq[2] + ssq[3];
  float mu = s * (1.0f/1024.0f);
  float var = sq * (1.0f/1024.0f) - mu*mu;
  float rs = rsqrtf(var + 1e-5f);
  u16x4 o;
  #pragma unroll
  for (int j = 0; j < 4; j++) {
    float y = (v[j] - mu) * rs * g[tid*4+j] + b[tid*4+j];
    o[j] = f2bf(y);
  }
  *(u16x4*)(out + (size_t)row * 1024 + tid * 4) = o;
}

// ---------------- fused: x1 = x + sum4(P); h2 = LN(x1)*g+b  (one row/block) ----------------
__global__ __launch_bounds__(256) void k_redln(const float* __restrict__ x, const u16* __restrict__ P,
                                               const float* __restrict__ g, const float* __restrict__ b,
                                               float* __restrict__ x1, u16* __restrict__ h2) {
  int row = blockIdx.x, tid = threadIdx.x;
  int wid = tid >> 6;
  size_t off = (size_t)row * 1024 + tid * 4;
  float4v v = *(const float4v*)(x + off);
  #pragma unroll
  for (int z = 0; z < 4; z++) {
    u16x4 p = *(const u16x4*)(P + (size_t)z * 4194304 + off);
    #pragma unroll
    for (int j = 0; j < 4; j++) v[j] += bf2f(p[j]);
  }
  *(float4v*)(x1 + off) = v;
  float s = v[0] + v[1] + v[2] + v[3];
  float sq = v[0]*v[0] + v[1]*v[1] + v[2]*v[2] + v[3]*v[3];
  #pragma unroll
  for (int m = 1; m <= 32; m <<= 1) { s += __shfl_xor(s, m); sq += __shfl_xor(sq, m); }
  __shared__ float ss[4], ssq[4];
  if ((tid & 63) == 0) { ss[wid] = s; ssq[wid] = sq; }
  __syncthreads();
  s = ss[0] + ss[1] + ss[2] + ss[3];
  sq = ssq[0] + ssq[1] + ssq[2] + ssq[3];
  float mu = s * (1.0f/1024.0f);
  float var = sq * (1.0f/1024.0f) - mu*mu;
  float rs = rsqrtf(var + 1e-5f);
  u16x4 o;
  #pragma unroll
  for (int j = 0; j < 4; j++) o[j] = f2bf((v[j] - mu) * rs * g[tid*4+j] + b[tid*4+j]);
  *(u16x4*)(h2 + off) = o;
}

// ================= 256x256 GEMM, BK=64, 8-phase half-tile pipeline (m201-derived) =================
// LDS layout: [buf][A|B][half 128 rows][64 k] = 2*2*2*16KB = 128KB. Row = 128B, chunk g of
// row r at slot g^(r&7) (linear dest + pre-swizzled source on stage; swizzled read).
// Per iteration u: tiles 2u (buf0, ph0-3) and 2u+1 (buf1, ph4-7), 16 MFMA (one C-quadrant)
// per phase. One 16KB half-tile staged per phase:
//   ph0:Ah0(tb->buf1) ph1:Ah1(tb) ph2:Bh0(t2->buf0) ph3:Bh1(t2)+VMW(4)
//   ph4:Ah0(t2) ph5:Ah1(t2) ph6:Bh0(t3->buf1) ph7:Bh1(t3)+VMW(4)
// In-order retire => VMW(4) guarantees the needed tile fully landed with 2 units in flight.
// All vmem ops in the counted windows are global_load_lds only.
// EPI: 2=bf16 gelu(acc+bias), 4=bf16 plain, 6=bf16 partial at z*M*N
template<int EPI>
__global__ __launch_bounds__(512, 2) void k_g256(const u16* __restrict__ A, const u16* __restrict__ B,
                                                 const float* __restrict__ bias, u16* __restrict__ Cb,
                                                 int M, int N, int K, int Ksub) {
  extern __shared__ __align__(16) u16 smem[];   // 128KB
  int tid = threadIdx.x;
  int gx = gridDim.x;
  int lin = blockIdx.y * gx + blockIdx.x;
  int nwg = gx * gridDim.y;
  int cpx = nwg >> 3;
  int swz = (lin & 7) * cpx + (lin >> 3);
  int bx = swz % gx, by = swz / gx;
  int m0 = by * 256, n0 = bx * 256;
  int kbase = blockIdx.z * Ksub;
  int wid = tid >> 6, lane = tid & 63;
  int wm = wid >> 2, wn = wid & 3;          // wave tile 128(M) x 64(N)
  int l15 = lane & 15, l16 = lane >> 4;

  f32x4 acc[8][4] = {};
  int ntile = Ksub >> 6;
  int nit = ntile >> 1;

  auto UNIT = [&](int buf, int mat, int half, int kt) {
    const u16* src = mat ? B : A;
    int rb = (mat ? n0 : m0) + half*128;
    u16* dstb = smem + buf*32768 + mat*16384 + half*8192;
    #pragma unroll
    for (int j = 0; j < 2; j++) {
      int c = j*512 + tid;
      int R = c >> 3, p = c & 7;
      int g = p ^ (R & 7);
      gload16(src + (size_t)(rb + R)*K + kbase + kt*64 + g*8, dstb + c*8);
    }
  };
  auto RDA = [&](short8* af, int buf, int mh) {   // 8 ds_read_b128 (wave's A-half = wm)
    const u16* ab = smem + buf*32768 + wm*8192;
    #pragma unroll
    for (int mf = 0; mf < 4; mf++)
      #pragma unroll
      for (int ks = 0; ks < 2; ks++) {
        int lr = mh*64 + mf*16 + l15;
        int s = (ks*4 + l16) ^ (lr & 7);
        af[mf*2 + ks] = *(const short8*)(ab + lr*64 + s*8);
      }
  };
  auto RDB = [&](short8* br, int buf, int nh) {   // 4 ds_read_b128 (wave's B-half = wn>>1)
    const u16* bb = smem + buf*32768 + 16384 + (wn >> 1)*8192;
    #pragma unroll
    for (int nf = 0; nf < 2; nf++)
      #pragma unroll
      for (int ks = 0; ks < 2; ks++) {
        int lr = (wn & 1)*64 + nh*32 + nf*16 + l15;
        int s = (ks*4 + l16) ^ (lr & 7);
        br[nf*2 + ks] = *(const short8*)(bb + lr*64 + s*8);
      }
  };
  auto QMF = [&](const short8* af, const short8* br, int mh, int nh) {
    __builtin_amdgcn_s_setprio(1);
    #pragma unroll
    for (int ks = 0; ks < 2; ks++)
      #pragma unroll
      for (int mf = 0; mf < 4; mf++)
        #pragma unroll
        for (int nf = 0; nf < 2; nf++)
          acc[mh*4+mf][nh*2+nf] = __builtin_amdgcn_mfma_f32_16x16x32_bf16(
              af[mf*2+ks], br[nf*2+ks], acc[mh*4+mf][nh*2+nf], 0, 0, 0);
    __builtin_amdgcn_s_setprio(0);
  };

  // prologue: tile0 all 4 units (buf0), tile1 B units (buf1) = 12 loads; VMW(4) -> tile0 landed
  UNIT(0,0,0,0); UNIT(0,0,1,0); UNIT(0,1,0,0); UNIT(0,1,1,0);
  UNIT(1,1,0,1); UNIT(1,1,1,1);
  VMW4_;
  __builtin_amdgcn_s_barrier();
  SBAR;

  short8 afr[8], b0r[4], b1r[4];
  for (int u = 0; u < nit; ++u) {
    int tb = 2*u + 1, t2 = 2*u + 2, t3 = 2*u + 3;
    bool has2 = (t2 < ntile), has3 = (t3 < ntile);
    // ---- tile 2u in buf0 ----
    // ph0: Q(0,0); stage buf1 Ah0(tb) [buf1 A free since prev ph6]
    RDA(afr, 0, 0); RDB(b0r, 0, 0);
    UNIT(1, 0, 0, tb);
    BARR_; LG0_; QMF(afr, b0r, 0, 0); BARR_;
    // ph1: Q(0,1); stage buf1 Ah1(tb)
    RDB(b1r, 0, 1);
    UNIT(1, 0, 1, tb);
    BARR_; LG0_; QMF(afr, b1r, 0, 1); BARR_;
    // ph2: Q(1,1); stage buf0 Bh0(t2) [buf0 B free after ph1]
    RDA(afr, 0, 1);
    if (has2) UNIT(0, 1, 0, t2);
    BARR_; LG0_; QMF(afr, b1r, 1, 1); BARR_;
    // ph3: Q(1,0); stage buf0 Bh1(t2); VMW(4): tile tb fully landed before ph4 reads
    if (has2) { UNIT(0, 1, 1, t2); VMW4_; } else { VMW0_; }
    BARR_; QMF(afr, b0r, 1, 0); BARR_;
    // ---- tile 2u+1 in buf1 ----
    // ph4: Q(0,0); stage buf0 Ah0(t2) [buf0 A free after ph2]
    RDA(afr, 1, 0); RDB(b0r, 1, 0);
    if (has2) UNIT(0, 0, 0, t2);
    BARR_; LG0_; QMF(afr, b0r, 0, 0); BARR_;
    // ph5: Q(0,1); stage buf0 Ah1(t2)
    RDB(b1r, 1, 1);
    if (has2) UNIT(0, 0, 1, t2);
    BARR_; LG0_; QMF(afr, b1r, 0, 1); BARR_;
    // ph6: Q(1,1); stage buf1 Bh0(t3) [buf1 B free after ph5]
    RDA(afr, 1, 1);
    if (has3) UNIT(1, 1, 0, t3);
    BARR_; LG0_; QMF(afr, b1r, 1, 1); BARR_;
    // ph7: Q(1,0); stage buf1 Bh1(t3); VMW(4): tile t2 fully landed before next ph0 reads
    if (has3) { UNIT(1, 1, 1, t3); VMW4_; } else { VMW0_; }
    BARR_; QMF(afr, b0r, 1, 0); BARR_;
  }

  size_t zoff = (EPI == 6) ? (size_t)blockIdx.z * M * N : 0;
  #pragma unroll
  for (int mf = 0; mf < 8; mf++) {
    #pragma unroll
    for (int nf = 0; nf < 4; nf++) {
      int col = n0 + wn*64 + nf*16 + l15;
      #pragma unroll
      for (int r = 0; r < 4; r++) {
        int row = m0 + wm*128 + mf*16 + l16*4 + r;
        float v = acc[mf][nf][r];
        if constexpr (EPI == 2) { v += bias[col]; v = 0.5f*v*(1.0f + erff(v*0.70710678118f)); }
        Cb[zoff + (size_t)row*N + col] = f2bf(v);
      }
    }
  }
}

// ---------------- reduce: out = base (+bias) + sum_{z<NP} P_z  (f32 out) ----------------
template<int NP, int HASB>
__global__ __launch_bounds__(256) void k_red(const float* __restrict__ base, const float* __restrict__ bias,
                                             const u16* __restrict__ P, size_t zstride, float* __restrict__ out) {
  int i = blockIdx.x * 256 + threadIdx.x;
  float4v v = *(const float4v*)(base + (size_t)i * 4);
  if constexpr (HASB) {
    float4v bb = *(const float4v*)(bias + (size_t)(i & 255) * 4);
    #pragma unroll
    for (int j = 0; j < 4; j++) v[j] += bb[j];
  }
  #pragma unroll
  for (int z = 0; z < NP; z++) {
    u16x4 p = *(const u16x4*)(P + (size_t)z * zstride + (size_t)i * 4);
    #pragma unroll
    for (int j = 0; j < 4; j++) v[j] += bf2f(p[j]);
  }
  *(float4v*)(out + (size_t)i * 4) = v;
}

// ---------------- prep: l2norm q,k (fold temp*log2e into q), V -> V^T ----------------
__global__ __launch_bounds__(256) void k_prep(const u16* __restrict__ qkv, const float* __restrict__ temp,
                                              u16* __restrict__ Qn, u16* __restrict__ Kn, u16* __restrict__ Vt) {
  int grp = blockIdx.x, bh = blockIdx.y;
  int b = bh >> 4, h = bh & 15;
  int tid = threadIdx.x;
  int n0 = grp * 64;
  __shared__ __align__(16) u16 vs[64*64];
  float tmp = temp[h] * 1.44269504f;
  int j8 = tid & 7;
  #pragma unroll
  for (int pass = 0; pass < 2; pass++) {
    int tl = pass*32 + (tid >> 3);
    size_t roff = (size_t)((b*2048) + n0 + tl) * 3072 + h*64 + j8*8;
    short8 q8 = *(const short8*)(qkv + roff);
    short8 k8 = *(const short8*)(qkv + roff + 1024);
    short8 v8 = *(const short8*)(qkv + roff + 2048);
    float qv[8], kv[8];
    float sq = 0.f, sk = 0.f;
    #pragma unroll
    for (int jj = 0; jj < 8; jj++) {
      qv[jj] = bf2f((u16)q8[jj]); sq += qv[jj]*qv[jj];
      kv[jj] = bf2f((u16)k8[jj]); sk += kv[jj]*kv[jj];
    }
    sq += __shfl_xor(sq, 1); sq += __shfl_xor(sq, 2); sq += __shfl_xor(sq, 4);
    sk += __shfl_xor(sk, 1); sk += __shfl_xor(sk, 2); sk += __shfl_xor(sk, 4);
    float qs = tmp / fmaxf(sqrtf(sq), 1e-12f);
    float ksc = 1.0f / fmaxf(sqrtf(sk), 1e-12f);
    short8 qo, ko;
    #pragma unroll
    for (int jj = 0; jj < 8; jj++) {
      qo[jj] = (short)f2bf(qv[jj] * qs);
      ko[jj] = (short)f2bf(kv[jj] * ksc);
    }
    size_t obase = ((size_t)bh*2048 + n0 + tl)*64 + j8*8;
    *(short8*)(Qn + obase) = qo;
    *(short8*)(Kn + obase) = ko;
    *(short8*)&vs[tl*64 + j8*8] = v8;
  }
  __syncthreads();
  int d = tid & 63, chunk = tid >> 6;
  u16 vals[16];
  #pragma unroll
  for (int jj = 0; jj < 16; jj++) vals[jj] = vs[(chunk*16 + jj)*64 + d];
  short8 w0, w1v;
  #pragma unroll
  for (int j = 0; j < 8; j++) { w0[j] = (short)vals[j]; w1v[j] = (short)vals[8+j]; }
  size_t vo = ((size_t)bh*64 + d)*2048 + n0 + chunk*16;
  *(short8*)(Vt + vo) = w0;
  *(short8*)(Vt + vo + 8) = w1v;
}

// ---------------- flash attention v5 (R20 green, unchanged) ----------------
__device__ __forceinline__ int akey(int row) { return (row & 3) | (((row >> 3) & 1) << 2); }

__global__ __launch_bounds__(256) void k_attn(const u16* __restrict__ Qn, const u16* __restrict__ Kn,
                                              const u16* __restrict__ Vt, const float* __restrict__ temp,
                                              u16* __restrict__ Out) {
  __shared__ __align__(16) u16 Ks[2][64*64];
  __shared__ __align__(16) u16 Vs[2][64*64];
  int lin = blockIdx.y * gridDim.x + blockIdx.x;
  int c = lin & 7, t5 = lin >> 3;
  int bh = c*4 + (t5 >> 4);
  int qg = t5 & 15;
  int b = bh >> 4, h = bh & 15;
  int tid = threadIdx.x, wid = tid >> 6, lane = tid & 63;
  int l15 = lane & 15, l16 = lane >> 4;
  size_t base = (size_t)bh * 2048 * 64;
  size_t vbase = (size_t)bh * 64 * 2048;
  int q0 = qg*128 + wid*32;
  float m2 = fabsf(temp[h]) * 1.44269504f;
  short8 qf[2][2];
  #pragma unroll
  for (int g = 0; g < 2; g++)
    #pragma unroll
    for (int ks = 0; ks < 2; ks++)
      qf[g][ks] = *(const short8*)(Qn + base + (size_t)(q0 + g*16 + l15)*64 + ks*32 + l16*8);
  f32x4 o[2][4] = {};
  float lrow[2] = {0.f, 0.f};
  int prow = (l15 & 3) + 8*(l15 >> 2);

  auto STAGE = [&](int bsel, int kv0) {
    #pragma unroll
    for (int i = 0; i < 2; i++) {
      int cc = i*256 + tid;
      int row = cc >> 3, p = cc & 7;
      int g = p ^ akey(row);
      gload16(Kn + base + (size_t)(kv0 + row)*64 + g*8, &Ks[bsel][(i*256 + wid*64)*8]);
      gload16(Vt + vbase + (size_t)row*2048 + kv0 + g*8, &Vs[bsel][(i*256 + wid*64)*8]);
    }
  };

  STAGE(0, 0);
  int cur = 0;
  for (int kv0 = 0; kv0 < 2048; kv0 += 64) {
    asm volatile("s_waitcnt vmcnt(0)" ::: "memory");
    SBAR;
    __builtin_amdgcn_s_barrier();
    SBAR;
    if (kv0 + 64 < 2048) STAGE(cur ^ 1, kv0 + 64);
    f32x4 s[2][4];
    #pragma unroll
    for (int g = 0; g < 2; g++)
      #pragma unroll
      for (int ss = 0; ss < 4; ss++)
        s[g][ss] = f32x4{-m2, -m2, -m2, -m2};
    __builtin_amdgcn_s_setprio(1);
    #pragma unroll
    for (int dks = 0; dks < 2; dks++) {
      #pragma unroll
      for (int ss = 0; ss < 4; ss++) {
        int row = (ss & 1)*4 + (ss >> 1)*32 + prow;
        short8 kf = *(const short8*)&Ks[cur][row*64 + ((dks*4 + l16) ^ akey(row))*8];
        s[0][ss] = __builtin_amdgcn_mfma_f32_16x16x32_bf16(kf, qf[0][dks], s[0][ss], 0, 0, 0);
        s[1][ss] = __builtin_amdgcn_mfma_f32_16x16x32_bf16(kf, qf[1][dks], s[1][ss], 0, 0, 0);
      }
    }
    __builtin_amdgcn_s_setprio(0);
    short8 pf[2][2];
    #pragma unroll
    for (int g = 0; g < 2; g++) {
      float tsum = 0.f;
      #pragma unroll
      for (int kvs = 0; kvs < 2; kvs++) {
        float e[8];
        #pragma unroll
        for (int r = 0; r < 4; r++) {
          e[r]   = fast_exp2(s[g][kvs*2][r]);
          e[4+r] = fast_exp2(s[g][kvs*2+1][r]);
        }
        #pragma unroll
        for (int r = 0; r < 8; r++) tsum += e[r];
        union { uint32_t u[4]; short8 v; } pu;
        #pragma unroll
        for (int w = 0; w < 4; w++) {
          uint32_t pk;
          asm("v_cvt_pk_bf16_f32 %0, %1, %2" : "=v"(pk) : "v"(e[2*w]), "v"(e[2*w+1]));
          pu.u[w] = pk;
        }
        pf[g][kvs] = pu.v;
      }
      lrow[g] += tsum;
    }
    __builtin_amdgcn_s_setprio(1);
    #pragma unroll
    for (int kvs = 0; kvs < 2; kvs++) {
      short8 vf[4];
      #pragma unroll
      for (int dt = 0; dt < 4; dt++) {
        int row = dt*16 + l15;
        vf[dt] = *(const short8*)&Vs[cur][row*64 + (((kvs*4 + l16) ^ akey(row))*8)];
      }
      #pragma unroll
      for (int dt = 0; dt < 4; dt++) {
        o[0][dt] = __builtin_amdgcn_mfma_f32_16x16x32_bf16(vf[dt], pf[0][kvs], o[0][dt], 0, 0, 0);
        o[1][dt] = __builtin_amdgcn_mfma_f32_16x16x32_bf16(vf[dt], pf[1][kvs], o[1][dt], 0, 0, 0);
      }
    }
    __builtin_amdgcn_s_setprio(0);
    cur ^= 1;
  }
  #pragma unroll
  for (int g = 0; g < 2; g++) {
    float l = lrow[g];
    l += __shfl_xor(l, 16);
    l += __shfl_xor(l, 32);
    float rl = 1.0f / l;
    int tok = b*2048 + q0 + g*16 + l15;
    #pragma unroll
    for (int dt = 0; dt < 4; dt++) {
      u16x4 ov;
      #pragma unroll
      for (int r = 0; r < 4; r++) ov[r] = f2bf(o[g][dt][r] * rl);
      *(u16x4*)(Out + (size_t)tok*1024 + h*64 + dt*16 + l16*4) = ov;
    }
  }
}

// ---------------- workspace layout (bytes) ----------------
static constexpr size_t OFF_WQKV  = 0;
static constexpr size_t OFF_WPROJ = OFF_WQKV  + 6291456;
static constexpr size_t OFF_W1    = OFF_WPROJ + 2097152;
static constexpr size_t OFF_W2    = OFF_W1    + 8388608;
static constexpr size_t OFF_HBF   = OFF_W2    + 8388608;
static constexpr size_t OFF_QKVBF = OFF_HBF   + 8388608;
static constexpr size_t OFF_QN    = OFF_QKVBF + 25165824;
static constexpr size_t OFF_KN    = OFF_QN    + 8388608;
static constexpr size_t OFF_VT    = OFF_KN    + 8388608;
static constexpr size_t OFF_AOUT  = OFF_VT    + 8388608;
static constexpr size_t OFF_H2BF  = OFF_AOUT  + 8388608;
static constexpr size_t OFF_X1    = OFF_H2BF  + 8388608;
static constexpr size_t OFF_HID   = OFF_X1    + 16777216;

extern "C" void kernel_launch(void* const* d_in, const int* in_sizes, int n_in,
                              void* d_out, int out_size, void* d_ws, size_t ws_size,
                              hipStream_t stream) {
  (void)in_sizes; (void)n_in; (void)out_size; (void)ws_size;
  const float* x     = (const float*)d_in[0];
  const float* ln1g  = (const float*)d_in[1];
  const float* ln1b  = (const float*)d_in[2];
  const float* wqkv  = (const float*)d_in[3];
  const float* wproj = (const float*)d_in[4];
  const float* temp  = (const float*)d_in[5];
  const float* ln2g  = (const float*)d_in[6];
  const float* ln2b  = (const float*)d_in[7];
  const float* w1    = (const float*)d_in[8];
  const float* b1    = (const float*)d_in[9];
  const float* w2    = (const float*)d_in[10];
  const float* b2    = (const float*)d_in[11];

  char* ws = (char*)d_ws;
  u16* wqkv_bf  = (u16*)(ws + OFF_WQKV);
  u16* wproj_bf = (u16*)(ws + OFF_WPROJ);
  u16* w1_bf    = (u16*)(ws + OFF_W1);
  u16* w2_bf    = (u16*)(ws + OFF_W2);
  u16* h_bf     = (u16*)(ws + OFF_HBF);
  u16* h2_bf    = (u16*)(ws + OFF_H2BF);
  u16* qkv_bf   = (u16*)(ws + OFF_QKVBF);
  u16* Qn       = (u16*)(ws + OFF_QN);
  u16* Kn       = (u16*)(ws + OFF_KN);
  u16* Vt       = (u16*)(ws + OFF_VT);
  u16* aout_bf  = (u16*)(ws + OFF_AOUT);
  float* x1     = (float*)(ws + OFF_X1);
  u16* hid_bf   = (u16*)(ws + OFF_HID);
  u16* part_p   = (u16*)(ws + OFF_HID);    // proj partials (hid dead then)
  u16* part_m   = (u16*)(ws + OFF_QN);     // mlp2 partials (QN..AOUT dead then)
  float* outf   = (float*)d_out;

  static bool attr_done = false;
  if (!attr_done) {
    hipFuncSetAttribute((const void*)k_g256<2>, hipFuncAttributeMaxDynamicSharedMemorySize, 131072);
    hipFuncSetAttribute((const void*)k_g256<4>, hipFuncAttributeMaxDynamicSharedMemorySize, 131072);
    hipFuncSetAttribute((const void*)k_g256<6>, hipFuncAttributeMaxDynamicSharedMemorySize, 131072);
    attr_done = true;
  }

  k_cvt4<<<2048, 256, 0, stream>>>(wqkv, wproj, w1, w2, wqkv_bf, wproj_bf, w1_bf, w2_bf);

  k_ln<<<4096, 256, 0, stream>>>(x, ln1g, ln1b, h_bf);
  k_g256<4><<<dim3(12, 16), 512, 131072, stream>>>(h_bf, wqkv_bf, nullptr, qkv_bf, 4096, 3072, 1024, 1024);
  k_prep<<<dim3(32, 32), 256, 0, stream>>>(qkv_bf, temp, Qn, Kn, Vt);
  k_attn<<<dim3(16, 32), 256, 0, stream>>>(Qn, Kn, Vt, temp, aout_bf);
  // proj split-K=4 partials (at HID) -> fused reduce + LN2
  k_g256<6><<<dim3(4, 16, 4), 512, 131072, stream>>>(aout_bf, wproj_bf, nullptr, part_p, 4096, 1024, 1024, 256);
  k_redln<<<4096, 256, 0, stream>>>(x, part_p, ln2g, ln2b, x1, h2_bf);
  // mlp1: hid = gelu(h2 @ w1^T + b1)
  k_g256<2><<<dim3(16, 16), 512, 131072, stream>>>(h2_bf, w1_bf, b1, hid_bf, 4096, 4096, 1024, 1024);
  // mlp2 split-K=4 partials -> out = x1 + b2 + sum4(P)
  k_g256<6><<<dim3(4, 16, 4), 512, 131072, stream>>>(hid_bf, w2_bf, nullptr, part_m, 4096, 1024, 4096, 1024);
  k_red<4,1><<<4096, 256, 0, stream>>>(x1, b2, part_m, 4194304, outf);
}